// Round 3
// baseline (417.912 us; speedup 1.0000x reference)
//
#include <hip/hip_runtime.h>
#include <hip/hip_bf16.h>

#define BLOCK   512     // 8 waves
#define NSAMP   16      // samples per block (= N of the per-node GEMM)
#define HDIM    128
#define DDIM    16
#define NOBJ    6
#define NNODES  63

typedef __attribute__((ext_vector_type(8))) short bf16x8;
typedef __attribute__((ext_vector_type(4))) float f32x4;

// ---- compile-time preorder DFS over sorted subsets ----
struct Tab { int obj[NNODES]; int depth[NNODES]; };
constexpr void tab_dfs(Tab& t, int& n, int maxel, int depth) {
    for (int j = maxel + 1; j < NOBJ; ++j) {
        t.obj[n] = j; t.depth[n] = depth; ++n;
        tab_dfs(t, n, j, depth + 1);
    }
}
constexpr Tab make_tab() { Tab t{}; int n = 0; tab_dfs(t, n, -1, 1); return t; }
constexpr Tab TAB = make_tab();

#define LOG2E  1.44269504f
#define TWOL2E 2.88539008f

// sigmoid(z+b), nb = -LOG2E*b : 2 trans, 2 VALU, saturates correctly at +-inf
__device__ __forceinline__ float fast_sig(float z, float nb) {
    float e = __builtin_amdgcn_exp2f(fmaf(-LOG2E, z, nb));
    return __builtin_amdgcn_rcpf(1.0f + e);
}
// tanh(z+b), tb = 2*LOG2E*b : tanh(y) = 1 - 2/(exp2(2*log2e*y)+1)
__device__ __forceinline__ float fast_tanh_b(float z, float tb) {
    float e = __builtin_amdgcn_exp2f(fmaf(TWOL2E, z, tb));
    float r = __builtin_amdgcn_rcpf(1.0f + e);
    return fmaf(-2.0f, r, 1.0f);
}
__device__ __forceinline__ float fast_tanh(float y) {
    float e = __builtin_amdgcn_exp2f(y * TWOL2E);
    float r = __builtin_amdgcn_rcpf(1.0f + e);
    return fmaf(-2.0f, r, 1.0f);
}
__device__ __forceinline__ unsigned short f2bf(float x) {
    union { float f; unsigned int u; } a; a.f = x;
    unsigned int r = (a.u + 0x7FFFu + ((a.u >> 16) & 1u)) >> 16;
    return (unsigned short)r;
}

// LDS h-stack: hs[((slot*16 + kslot)*16 + n)*8 + j] = h[k = kslot*8+j][sample n]
// B-fragment chunk q for lane (quad,n): kslot = q*4+quad -> one 16B-aligned b128.

__global__ __launch_bounds__(BLOCK, 4)
void subset_lstm_mfma_kernel(
    const float* __restrict__ x_input,
    const float* __restrict__ W_ih,
    const float* __restrict__ W_hh,
    const float* __restrict__ b_ih,
    const float* __restrict__ b_hh,
    const float* __restrict__ fc1_W,
    const float* __restrict__ fc1_b,
    const float* __restrict__ fc2_W,
    const float* __restrict__ fc2_b,
    float* __restrict__ out)
{
    __shared__ __align__(16) unsigned short hs[5 * 16 * NSAMP * 8];   // 20 KB
    __shared__ __align__(16) unsigned short xb[NOBJ * 4 * NSAMP * 8]; // 6 KB
    __shared__ float s_maxh[NSAMP * HDIM];                            // 8 KB
    float* s_fc1   = (float*)hs;   // [16][256] alias after LSTM phase
    float* s_logit = (float*)xb;   // [16][10]  alias after LSTM phase

    const int t      = threadIdx.x;
    const int w      = t >> 6;
    const int lane   = t & 63;
    const int quad   = lane >> 4;
    const int m16    = lane & 15;
    const int s_base = blockIdx.x * NSAMP;

    // ---- x B-chunks: xb[obj][quad'][n][j]; quads 2,3 zero-padded ----
    for (int idx = t; idx < NOBJ * 2 * NSAMP * 8; idx += BLOCK) {
        const int j   = idx & 7;
        const int n   = (idx >> 3) & 15;
        const int q   = (idx >> 7) & 1;
        const int obj = idx >> 8;
        xb[((obj * 4 + q) * NSAMP + n) * 8 + j] =
            f2bf(x_input[(s_base + n) * (NOBJ * DDIM) + obj * DDIM + q * 8 + j]);
        xb[((obj * 4 + 2 + q) * NSAMP + n) * 8 + j] = 0;
    }

    // ---- persistent weight A-fragments wf[gate][kchunk] ----
    bf16x8 wf[4][5];
    #pragma unroll
    for (int g = 0; g < 4; ++g) {
        const int r = g * HDIM + w * 16 + m16;
        const float* whr = W_hh + r * HDIM;
        const float* wir = W_ih + r * DDIM;
        #pragma unroll
        for (int q = 0; q < 4; ++q) {
            union { unsigned short u[8]; bf16x8 v; } pk;
            #pragma unroll
            for (int j = 0; j < 8; ++j)
                pk.u[j] = f2bf(whr[q * 32 + quad * 8 + j]);
            wf[g][q] = pk.v;
        }
        {
            union { unsigned short u[8]; bf16x8 v; } pk;
            #pragma unroll
            for (int j = 0; j < 8; ++j) {
                float v = 0.0f;
                if (quad == 0) v = wir[j];
                else if (quad == 1) v = wir[8 + j];
                pk.u[j] = f2bf(v);
            }
            wf[g][4] = pk.v;
        }
    }

    // pre-scaled biases: gates i,f,o -> -LOG2E*b ; gate g -> 2*LOG2E*b
    float bia[4][4];
    #pragma unroll
    for (int g = 0; g < 4; ++g)
        #pragma unroll
        for (int r = 0; r < 4; ++r) {
            const int c = w * 16 + quad * 4 + r;
            const float b = b_ih[g * HDIM + c] + b_hh[g * HDIM + c];
            bia[g][r] = (g == 2) ? TWOL2E * b : -LOG2E * b;
        }

    float cst[5][4];
    float mh[4] = {-1e30f, -1e30f, -1e30f, -1e30f};

    #pragma unroll
    for (int nd = 0; nd < NNODES; ++nd) {
        const int jo = TAB.obj[nd];    // compile-time after unroll
        const int d  = TAB.depth[nd];

        __syncthreads();

        f32x4 acc[4];
        #pragma unroll
        for (int g = 0; g < 4; ++g)
            acc[g] = f32x4{0.f, 0.f, 0.f, 0.f};

        if (d >= 2) {
            const int slot = d - 2;
            #pragma unroll
            for (int q = 0; q < 4; ++q) {
                const bf16x8 bfrag = *(const bf16x8*)
                    &hs[(((slot * 16) + q * 4 + quad) * NSAMP + m16) * 8];
                #pragma unroll
                for (int g = 0; g < 4; ++g)
                    acc[g] = __builtin_amdgcn_mfma_f32_16x16x32_bf16(
                        wf[g][q], bfrag, acc[g], 0, 0, 0);
            }
        }
        {
            const bf16x8 bfrag = *(const bf16x8*)
                &xb[((jo * 4 + quad) * NSAMP + m16) * 8];
            #pragma unroll
            for (int g = 0; g < 4; ++g)
                acc[g] = __builtin_amdgcn_mfma_f32_16x16x32_bf16(
                    wf[g][4], bfrag, acc[g], 0, 0, 0);
        }

        float hn[4];
        #pragma unroll
        for (int r = 0; r < 4; ++r) {
            const float cprev = (d >= 2) ? cst[d - 2][r] : 0.0f;  // static index
            const float ig = fast_sig(acc[0][r], bia[0][r]);
            const float fg = fast_sig(acc[1][r], bia[1][r]);
            const float gg = fast_tanh_b(acc[2][r], bia[2][r]);
            const float og = fast_sig(acc[3][r], bia[3][r]);
            const float cn = fmaf(fg, cprev, ig * gg);
            const float h  = og * fast_tanh(cn);
            hn[r] = h;
            mh[r] = fmaxf(mh[r], h);
            if (jo < NOBJ - 1) cst[d - 1][r] = cn;   // only if node has children
        }

        if (jo < NOBJ - 1) {   // h needed only by children
            union { __hip_bfloat162 h2[2]; uint2 v; } hp;
            hp.h2[0] = __float22bfloat162_rn(float2{hn[0], hn[1]});
            hp.h2[1] = __float22bfloat162_rn(float2{hn[2], hn[3]});
            const int kslot = w * 2 + (quad >> 1);
            unsigned short* dst =
                &hs[((((d - 1) * 16) + kslot) * NSAMP + m16) * 8 + (quad & 1) * 4];
            *(uint2*)dst = hp.v;
        }
    }

    __syncthreads();
    #pragma unroll
    for (int r = 0; r < 4; ++r) {
        const int c = w * 16 + quad * 4 + r;
        s_maxh[m16 * HDIM + c] = mh[r];
    }
    __syncthreads();

    // ---- FC1: thread t -> feature f = t&255, sample half t>>8 ----
    {
        const int f  = t & 255;
        const int sh = t >> 8;          // 0/1 -> samples sh*8 .. sh*8+7
        float a1[8];
        #pragma unroll
        for (int s = 0; s < 8; ++s) a1[s] = fc1_b[f];
        for (int k4 = 0; k4 < HDIM / 4; ++k4) {
            const float4 wv = *(const float4*)&fc1_W[f * HDIM + k4 * 4];
            #pragma unroll
            for (int s = 0; s < 8; ++s) {
                const float4 h4 = *(const float4*)&s_maxh[(sh * 8 + s) * HDIM + k4 * 4];
                a1[s] += wv.x * h4.x + wv.y * h4.y + wv.z * h4.z + wv.w * h4.w;
            }
        }
        #pragma unroll
        for (int s = 0; s < 8; ++s)
            s_fc1[(sh * 8 + s) * 256 + f] = fmaxf(a1[s], 0.0f);
    }
    __syncthreads();

    if (t < NSAMP * 10) {
        const int s = t / 10, a = t % 10;
        float acc2 = fc2_b[a];
        for (int f4 = 0; f4 < 256 / 4; ++f4) {
            const float4 wv = *(const float4*)&fc2_W[a * 256 + f4 * 4];
            const float4 v  = *(const float4*)&s_fc1[s * 256 + f4 * 4];
            acc2 += wv.x * v.x + wv.y * v.y + wv.z * v.z + wv.w * v.w;
        }
        s_logit[s * 10 + a] = acc2;
    }
    __syncthreads();

    if (t < NSAMP) {
        float m = -1e30f;
        #pragma unroll
        for (int a = 0; a < 10; ++a) m = fmaxf(m, s_logit[t * 10 + a]);
        float sum = 0.0f;
        #pragma unroll
        for (int a = 0; a < 10; ++a) sum += __expf(s_logit[t * 10 + a] - m);
        const float lse = m + __logf(sum);
        #pragma unroll
        for (int a = 0; a < 10; ++a)
            out[(s_base + t) * 10 + a] = s_logit[t * 10 + a] - lse;
    }
}

extern "C" void kernel_launch(void* const* d_in, const int* in_sizes, int n_in,
                              void* d_out, int out_size, void* d_ws, size_t ws_size,
                              hipStream_t stream)
{
    (void)d_ws; (void)ws_size; (void)n_in; (void)out_size;

    const float* x   = (const float*)d_in[0];
    const float* Wih = (const float*)d_in[1];
    const float* Whh = (const float*)d_in[2];
    const float* bih = (const float*)d_in[3];
    const float* bhh = (const float*)d_in[4];
    const float* f1w = (const float*)d_in[5];
    const float* f1b = (const float*)d_in[6];
    const float* f2w = (const float*)d_in[7];
    const float* f2b = (const float*)d_in[8];

    const int mb = in_sizes[0] / (NOBJ * DDIM);   // 8192
    dim3 grid(mb / NSAMP), block(BLOCK);
    subset_lstm_mfma_kernel<<<grid, block, 0, stream>>>(
        x, Wih, Whh, bih, bhh, f1w, f1b, f2w, f2b, (float*)d_out);
}

// Round 4
// 216.398 us; speedup vs baseline: 1.9312x; 1.9312x over previous
//
#include <hip/hip_runtime.h>
#include <hip/hip_bf16.h>

#define BLOCK   512     // 8 waves
#define NSAMP   16      // samples per block (= N of the per-node GEMM)
#define HDIM    128
#define DDIM    16
#define NOBJ    6
#define NNODES  63

typedef __attribute__((ext_vector_type(8))) short bf16x8;
typedef __attribute__((ext_vector_type(4))) float f32x4;

// ---- compile-time preorder DFS over sorted subsets ----
struct Tab { int obj[NNODES]; int depth[NNODES]; };
constexpr void tab_dfs(Tab& t, int& n, int maxel, int depth) {
    for (int j = maxel + 1; j < NOBJ; ++j) {
        t.obj[n] = j; t.depth[n] = depth; ++n;
        tab_dfs(t, n, j, depth + 1);
    }
}
constexpr Tab make_tab() { Tab t{}; int n = 0; tab_dfs(t, n, -1, 1); return t; }
constexpr Tab TAB = make_tab();

#define LOG2E  1.44269504f
#define TWOL2E 2.88539008f

// sigmoid(z+b), nb = -LOG2E*b : 2 trans + 2 VALU, saturates at +-inf
__device__ __forceinline__ float fast_sig(float z, float nb) {
    float e = __builtin_amdgcn_exp2f(fmaf(-LOG2E, z, nb));
    return __builtin_amdgcn_rcpf(1.0f + e);
}
// tanh(z+b), tb = 2*LOG2E*b : tanh(y) = 1 - 2/(exp2(2*log2e*y)+1)
__device__ __forceinline__ float fast_tanh_b(float z, float tb) {
    float e = __builtin_amdgcn_exp2f(fmaf(TWOL2E, z, tb));
    float r = __builtin_amdgcn_rcpf(1.0f + e);
    return fmaf(-2.0f, r, 1.0f);
}
__device__ __forceinline__ float fast_tanh(float y) {
    float e = __builtin_amdgcn_exp2f(y * TWOL2E);
    float r = __builtin_amdgcn_rcpf(1.0f + e);
    return fmaf(-2.0f, r, 1.0f);
}
__device__ __forceinline__ unsigned short f2bf(float x) {
    union { float f; unsigned int u; } a; a.f = x;
    unsigned int r = (a.u + 0x7FFFu + ((a.u >> 16) & 1u)) >> 16;
    return (unsigned short)r;
}

// LDS h-stack: hs[((slot*16 + kslot)*16 + n)*8 + j] = h[k = kslot*8+j][sample n]
// B-fragment chunk q for lane (quad,n): kslot = q*4+quad -> one 16B-aligned b128.

__global__ __launch_bounds__(BLOCK, 2)   // 2 waves/EU min: VGPR cap 256 (known-good, no spill)
void subset_lstm_mfma_kernel(
    const float* __restrict__ x_input,
    const float* __restrict__ W_ih,
    const float* __restrict__ W_hh,
    const float* __restrict__ b_ih,
    const float* __restrict__ b_hh,
    const float* __restrict__ fc1_W,
    const float* __restrict__ fc1_b,
    const float* __restrict__ fc2_W,
    const float* __restrict__ fc2_b,
    float* __restrict__ out)
{
    __shared__ __align__(16) unsigned short hs[5 * 16 * NSAMP * 8];   // 20 KB
    __shared__ __align__(16) unsigned short xb[NOBJ * 4 * NSAMP * 8]; // 6 KB
    __shared__ float s_maxh[NSAMP * HDIM];                            // 8 KB
    float* s_fc1   = (float*)hs;   // [16][256] alias after LSTM phase
    float* s_logit = (float*)xb;   // [16][10]  alias after LSTM phase

    const int t      = threadIdx.x;
    const int w      = t >> 6;
    const int lane   = t & 63;
    const int quad   = lane >> 4;
    const int m16    = lane & 15;
    const int s_base = blockIdx.x * NSAMP;

    // ---- x B-chunks: xb[obj][quad'][n][j]; quads 2,3 zero-padded ----
    for (int idx = t; idx < NOBJ * 2 * NSAMP * 8; idx += BLOCK) {
        const int j   = idx & 7;
        const int n   = (idx >> 3) & 15;
        const int q   = (idx >> 7) & 1;
        const int obj = idx >> 8;
        xb[((obj * 4 + q) * NSAMP + n) * 8 + j] =
            f2bf(x_input[(s_base + n) * (NOBJ * DDIM) + obj * DDIM + q * 8 + j]);
        xb[((obj * 4 + 2 + q) * NSAMP + n) * 8 + j] = 0;
    }

    // ---- persistent weight A-fragments wf[gate][kchunk] (80 VGPRs) ----
    bf16x8 wf[4][5];
    #pragma unroll
    for (int g = 0; g < 4; ++g) {
        const int r = g * HDIM + w * 16 + m16;
        const float* whr = W_hh + r * HDIM;
        const float* wir = W_ih + r * DDIM;
        #pragma unroll
        for (int q = 0; q < 4; ++q) {
            union { unsigned short u[8]; bf16x8 v; } pk;
            #pragma unroll
            for (int j = 0; j < 8; ++j)
                pk.u[j] = f2bf(whr[q * 32 + quad * 8 + j]);
            wf[g][q] = pk.v;
        }
        {
            union { unsigned short u[8]; bf16x8 v; } pk;
            #pragma unroll
            for (int j = 0; j < 8; ++j) {
                float v = 0.0f;
                if (quad == 0) v = wir[j];
                else if (quad == 1) v = wir[8 + j];
                pk.u[j] = f2bf(v);
            }
            wf[g][4] = pk.v;
        }
    }

    // pre-scaled biases: gates i,f,o -> -LOG2E*b ; gate g -> 2*LOG2E*b
    float bia[4][4];
    #pragma unroll
    for (int g = 0; g < 4; ++g)
        #pragma unroll
        for (int r = 0; r < 4; ++r) {
            const int c = w * 16 + quad * 4 + r;
            const float b = b_ih[g * HDIM + c] + b_hh[g * HDIM + c];
            bia[g][r] = (g == 2) ? TWOL2E * b : -LOG2E * b;
        }

    float cst[5][4];
    float mh[4] = {-1e30f, -1e30f, -1e30f, -1e30f};

    #pragma unroll
    for (int nd = 0; nd < NNODES; ++nd) {
        const int jo = TAB.obj[nd];    // compile-time constants after unroll
        const int d  = TAB.depth[nd];

        __syncthreads();

        f32x4 acc[4];
        #pragma unroll
        for (int g = 0; g < 4; ++g)
            acc[g] = f32x4{0.f, 0.f, 0.f, 0.f};

        if (d >= 2) {
            const int slot = d - 2;
            #pragma unroll
            for (int q = 0; q < 4; ++q) {
                const bf16x8 bfrag = *(const bf16x8*)
                    &hs[(((slot * 16) + q * 4 + quad) * NSAMP + m16) * 8];
                #pragma unroll
                for (int g = 0; g < 4; ++g)
                    acc[g] = __builtin_amdgcn_mfma_f32_16x16x32_bf16(
                        wf[g][q], bfrag, acc[g], 0, 0, 0);
            }
        }
        {
            const bf16x8 bfrag = *(const bf16x8*)
                &xb[((jo * 4 + quad) * NSAMP + m16) * 8];
            #pragma unroll
            for (int g = 0; g < 4; ++g)
                acc[g] = __builtin_amdgcn_mfma_f32_16x16x32_bf16(
                    wf[g][4], bfrag, acc[g], 0, 0, 0);
        }

        float hn[4];
        #pragma unroll
        for (int r = 0; r < 4; ++r) {
            const float cprev = (d >= 2) ? cst[d - 2][r] : 0.0f;  // static index
            const float ig = fast_sig(acc[0][r], bia[0][r]);
            const float fg = fast_sig(acc[1][r], bia[1][r]);
            const float gg = fast_tanh_b(acc[2][r], bia[2][r]);
            const float og = fast_sig(acc[3][r], bia[3][r]);
            const float cn = fmaf(fg, cprev, ig * gg);
            const float h  = og * fast_tanh(cn);
            hn[r] = h;
            mh[r] = fmaxf(mh[r], h);
            if (jo < NOBJ - 1) cst[d - 1][r] = cn;   // only if node has children
        }

        if (jo < NOBJ - 1) {   // h needed only by children
            union { __hip_bfloat162 h2[2]; uint2 v; } hp;
            hp.h2[0] = __float22bfloat162_rn(float2{hn[0], hn[1]});
            hp.h2[1] = __float22bfloat162_rn(float2{hn[2], hn[3]});
            const int kslot = w * 2 + (quad >> 1);
            unsigned short* dst =
                &hs[((((d - 1) * 16) + kslot) * NSAMP + m16) * 8 + (quad & 1) * 4];
            *(uint2*)dst = hp.v;
        }
    }

    __syncthreads();
    #pragma unroll
    for (int r = 0; r < 4; ++r) {
        const int c = w * 16 + quad * 4 + r;
        s_maxh[m16 * HDIM + c] = mh[r];
    }
    __syncthreads();

    // ---- FC1: thread t -> feature f = t&255, sample half t>>8 ----
    {
        const int f  = t & 255;
        const int sh = t >> 8;
        float a1[8];
        #pragma unroll
        for (int s = 0; s < 8; ++s) a1[s] = fc1_b[f];
        for (int k4 = 0; k4 < HDIM / 4; ++k4) {
            const float4 wv = *(const float4*)&fc1_W[f * HDIM + k4 * 4];
            #pragma unroll
            for (int s = 0; s < 8; ++s) {
                const float4 h4 = *(const float4*)&s_maxh[(sh * 8 + s) * HDIM + k4 * 4];
                a1[s] += wv.x * h4.x + wv.y * h4.y + wv.z * h4.z + wv.w * h4.w;
            }
        }
        #pragma unroll
        for (int s = 0; s < 8; ++s)
            s_fc1[(sh * 8 + s) * 256 + f] = fmaxf(a1[s], 0.0f);
    }
    __syncthreads();

    if (t < NSAMP * 10) {
        const int s = t / 10, a = t % 10;
        float acc2 = fc2_b[a];
        for (int f4 = 0; f4 < 256 / 4; ++f4) {
            const float4 wv = *(const float4*)&fc2_W[a * 256 + f4 * 4];
            const float4 v  = *(const float4*)&s_fc1[s * 256 + f4 * 4];
            acc2 += wv.x * v.x + wv.y * v.y + wv.z * v.z + wv.w * v.w;
        }
        s_logit[s * 10 + a] = acc2;
    }
    __syncthreads();

    if (t < NSAMP) {
        float m = -1e30f;
        #pragma unroll
        for (int a = 0; a < 10; ++a) m = fmaxf(m, s_logit[t * 10 + a]);
        float sum = 0.0f;
        #pragma unroll
        for (int a = 0; a < 10; ++a) sum += __expf(s_logit[t * 10 + a] - m);
        const float lse = m + __logf(sum);
        #pragma unroll
        for (int a = 0; a < 10; ++a)
            out[(s_base + t) * 10 + a] = s_logit[t * 10 + a] - lse;
    }
}

extern "C" void kernel_launch(void* const* d_in, const int* in_sizes, int n_in,
                              void* d_out, int out_size, void* d_ws, size_t ws_size,
                              hipStream_t stream)
{
    (void)d_ws; (void)ws_size; (void)n_in; (void)out_size;

    const float* x   = (const float*)d_in[0];
    const float* Wih = (const float*)d_in[1];
    const float* Whh = (const float*)d_in[2];
    const float* bih = (const float*)d_in[3];
    const float* bhh = (const float*)d_in[4];
    const float* f1w = (const float*)d_in[5];
    const float* f1b = (const float*)d_in[6];
    const float* f2w = (const float*)d_in[7];
    const float* f2b = (const float*)d_in[8];

    const int mb = in_sizes[0] / (NOBJ * DDIM);   // 8192
    dim3 grid(mb / NSAMP), block(BLOCK);
    subset_lstm_mfma_kernel<<<grid, block, 0, stream>>>(
        x, Wih, Whh, bih, bhh, f1w, f1b, f2w, f2b, (float*)d_out);
}

// Round 5
// 211.078 us; speedup vs baseline: 1.9799x; 1.0252x over previous
//
#include <hip/hip_runtime.h>
#include <hip/hip_bf16.h>

#define BLOCK   512     // 8 waves
#define NSAMP   16      // samples per block (= N of each per-node MFMA tile)
#define HDIM    128
#define DDIM    16
#define NOBJ    6

typedef __attribute__((ext_vector_type(8))) short bf16x8;
typedef __attribute__((ext_vector_type(4))) float f32x4;

// ---- compile-time BFS level tables over the 63 subsets ----
// Node = subset mask. Appended element jo = msb(mask); parent = mask without msb.
// Childful (has children) iff jo < 5. Childful nodes get slot ids per level.
constexpr int msb6(int m) { int b = -1; for (int i = 0; i < 6; ++i) if (m & (1 << i)) b = i; return b; }

struct BfsTab {
    int cnt[7];         // nodes per level
    int jo[7][20];      // appended element
    int pslot[7][20];   // parent's childful slot at level d-1 (-1 at d=1)
    int slot[7][20];    // this node's childful slot, or -1 if leaf
};
constexpr BfsTab make_bfs() {
    BfsTab t{};
    int slotOf[64] = {};
    for (int d = 1; d <= 6; ++d) {
        int n = 0, cf = 0;
        for (int M = 1; M < 64; ++M) {
            if (__builtin_popcount(M) != d) continue;
            const int hi = msb6(M);
            t.jo[d][n] = hi;
            t.pslot[d][n] = (d == 1) ? -1 : slotOf[M & ~(1 << hi)];
            if (hi < 5) { t.slot[d][n] = cf; slotOf[M] = cf; ++cf; }
            else t.slot[d][n] = -1;
            ++n;
        }
        t.cnt[d] = n;
    }
    return t;
}
constexpr BfsTab BT = make_bfs();

#define LOG2E   1.44269504f
#define TWOL2E  2.88539008f
#define SLOT_SZ (16 * NSAMP * 8)        // shorts per node slot (4 KB)
#define EVEN_OFF (10 * SLOT_SZ)         // bufEven after 10 odd slots

__device__ __forceinline__ float fast_sig(float z, float nb) {
    float e = __builtin_amdgcn_exp2f(fmaf(-LOG2E, z, nb));
    return __builtin_amdgcn_rcpf(1.0f + e);
}
__device__ __forceinline__ float fast_tanh_b(float z, float tb) {
    float e = __builtin_amdgcn_exp2f(fmaf(TWOL2E, z, tb));
    float r = __builtin_amdgcn_rcpf(1.0f + e);
    return fmaf(-2.0f, r, 1.0f);
}
__device__ __forceinline__ float fast_tanh(float y) {
    float e = __builtin_amdgcn_exp2f(y * TWOL2E);
    float r = __builtin_amdgcn_rcpf(1.0f + e);
    return fmaf(-2.0f, r, 1.0f);
}
__device__ __forceinline__ unsigned short f2bf(float x) {
    union { float f; unsigned int u; } a; a.f = x;
    unsigned int r = (a.u + 0x7FFFu + ((a.u >> 16) & 1u)) >> 16;
    return (unsigned short)r;
}

__global__ __launch_bounds__(BLOCK, 2)   // VGPR cap 256; 1 block/CU expected (LDS 86 KB)
void subset_lstm_bfs_kernel(
    const float* __restrict__ x_input,
    const float* __restrict__ W_ih,
    const float* __restrict__ W_hh,
    const float* __restrict__ b_ih,
    const float* __restrict__ b_hh,
    const float* __restrict__ fc1_W,
    const float* __restrict__ fc1_b,
    const float* __restrict__ fc2_W,
    const float* __restrict__ fc2_b,
    float* __restrict__ out)
{
    // bufOdd = slots 0..9 (levels 1,3,5), bufEven = slots 10..19 (levels 2,4)
    __shared__ __align__(16) unsigned short hsbuf[20 * SLOT_SZ];       // 80 KB
    __shared__ __align__(16) unsigned short xb[NOBJ * 4 * NSAMP * 8];  // 6 KB
    float* s_maxh  = (float*)(hsbuf + EVEN_OFF);  // 8 KB alias, post-loop only
    float* s_fc1   = (float*)hsbuf;               // 16 KB alias, post-loop only
    float* s_logit = (float*)xb;                  // post-FC alias

    const int t      = threadIdx.x;
    const int w      = t >> 6;
    const int lane   = t & 63;
    const int quad   = lane >> 4;
    const int m16    = lane & 15;
    const int s_base = blockIdx.x * NSAMP;

    // ---- x B-chunks: xb[obj][quad'][n][j]; quads 2,3 zero-padded ----
    for (int idx = t; idx < NOBJ * 2 * NSAMP * 8; idx += BLOCK) {
        const int j   = idx & 7;
        const int n   = (idx >> 3) & 15;
        const int q   = (idx >> 7) & 1;
        const int obj = idx >> 8;
        xb[((obj * 4 + q) * NSAMP + n) * 8 + j] =
            f2bf(x_input[(s_base + n) * (NOBJ * DDIM) + obj * DDIM + q * 8 + j]);
        xb[((obj * 4 + 2 + q) * NSAMP + n) * 8 + j] = 0;
    }

    // ---- persistent weight A-fragments wf[gate][kchunk] (80 VGPRs) ----
    bf16x8 wf[4][5];
    #pragma unroll
    for (int g = 0; g < 4; ++g) {
        const int r = g * HDIM + w * 16 + m16;
        const float* whr = W_hh + r * HDIM;
        const float* wir = W_ih + r * DDIM;
        #pragma unroll
        for (int q = 0; q < 4; ++q) {
            union { unsigned short u[8]; bf16x8 v; } pk;
            #pragma unroll
            for (int j = 0; j < 8; ++j)
                pk.u[j] = f2bf(whr[q * 32 + quad * 8 + j]);
            wf[g][q] = pk.v;
        }
        {
            union { unsigned short u[8]; bf16x8 v; } pk;
            #pragma unroll
            for (int j = 0; j < 8; ++j) {
                float v = 0.0f;
                if (quad == 0) v = wir[j];
                else if (quad == 1) v = wir[8 + j];
                pk.u[j] = f2bf(v);
            }
            wf[g][4] = pk.v;
        }
    }

    // pre-scaled biases: gates i,f,o -> -LOG2E*b ; gate g -> 2*LOG2E*b
    float bia[4][4];
    #pragma unroll
    for (int g = 0; g < 4; ++g)
        #pragma unroll
        for (int r = 0; r < 4; ++r) {
            const int c = w * 16 + quad * 4 + r;
            const float b = b_ih[g * HDIM + c] + b_hh[g * HDIM + c];
            bia[g][r] = (g == 2) ? TWOL2E * b : -LOG2E * b;
        }

    // c-state ping-pong in registers (static indices only after unroll)
    float cA[10][4];   // odd levels  (L1: 0..4, L3: 0..9, L5: 0)
    float cB[10][4];   // even levels (L2: 0..9, L4: 0..4)
    float mh[4] = {-1e30f, -1e30f, -1e30f, -1e30f};

    #pragma unroll
    for (int d = 1; d <= 6; ++d) {
        __syncthreads();   // previous level's h writes (and xb at d=1) visible

        unsigned short*       curbuf = hsbuf + ((d & 1) ? 0 : EVEN_OFF);
        const unsigned short* parbuf = hsbuf + (((d - 1) & 1) ? 0 : EVEN_OFF);

        #pragma unroll
        for (int ni = 0; ni < BT.cnt[d]; ++ni) {
            const int jo = BT.jo[d][ni];       // compile-time constants
            const int ps = BT.pslot[d][ni];
            const int sl = BT.slot[d][ni];

            f32x4 acc[4];
            #pragma unroll
            for (int g = 0; g < 4; ++g)
                acc[g] = f32x4{0.f, 0.f, 0.f, 0.f};

            if (d >= 2) {
                #pragma unroll
                for (int q = 0; q < 4; ++q) {
                    const bf16x8 bfrag = *(const bf16x8*)
                        &parbuf[ps * SLOT_SZ + (((q * 4 + quad) * NSAMP) + m16) * 8];
                    #pragma unroll
                    for (int g = 0; g < 4; ++g)
                        acc[g] = __builtin_amdgcn_mfma_f32_16x16x32_bf16(
                            wf[g][q], bfrag, acc[g], 0, 0, 0);
                }
            }
            {
                const bf16x8 bfrag = *(const bf16x8*)
                    &xb[((jo * 4 + quad) * NSAMP + m16) * 8];
                #pragma unroll
                for (int g = 0; g < 4; ++g)
                    acc[g] = __builtin_amdgcn_mfma_f32_16x16x32_bf16(
                        wf[g][4], bfrag, acc[g], 0, 0, 0);
            }

            float hn[4];
            #pragma unroll
            for (int r = 0; r < 4; ++r) {
                float cprev = 0.0f;
                if (d >= 2) cprev = ((d - 1) & 1) ? cA[ps][r] : cB[ps][r];
                const float ig = fast_sig(acc[0][r], bia[0][r]);
                const float fg = fast_sig(acc[1][r], bia[1][r]);
                const float gg = fast_tanh_b(acc[2][r], bia[2][r]);
                const float og = fast_sig(acc[3][r], bia[3][r]);
                const float cn = fmaf(fg, cprev, ig * gg);
                const float h  = og * fast_tanh(cn);
                hn[r] = h;
                mh[r] = fmaxf(mh[r], h);
                if (sl >= 0) {
                    if (d & 1) cA[sl][r] = cn; else cB[sl][r] = cn;
                }
            }

            if (sl >= 0) {   // h needed only by children
                union { __hip_bfloat162 h2[2]; uint2 v; } hp;
                hp.h2[0] = __float22bfloat162_rn(float2{hn[0], hn[1]});
                hp.h2[1] = __float22bfloat162_rn(float2{hn[2], hn[3]});
                const int kslot = w * 2 + (quad >> 1);
                unsigned short* dst =
                    &curbuf[sl * SLOT_SZ + ((kslot * NSAMP) + m16) * 8 + (quad & 1) * 4];
                *(uint2*)dst = hp.v;
            }
        }
    }

    __syncthreads();   // all levels done; hsbuf dead -> reuse for epilogue
    #pragma unroll
    for (int r = 0; r < 4; ++r) {
        const int c = w * 16 + quad * 4 + r;
        s_maxh[m16 * HDIM + c] = mh[r];
    }
    __syncthreads();

    // ---- FC1: thread t -> feature f = t&255, sample half t>>8 ----
    {
        const int f  = t & 255;
        const int sh = t >> 8;
        float a1[8];
        #pragma unroll
        for (int s = 0; s < 8; ++s) a1[s] = fc1_b[f];
        for (int k4 = 0; k4 < HDIM / 4; ++k4) {
            const float4 wv = *(const float4*)&fc1_W[f * HDIM + k4 * 4];
            #pragma unroll
            for (int s = 0; s < 8; ++s) {
                const float4 h4 = *(const float4*)&s_maxh[(sh * 8 + s) * HDIM + k4 * 4];
                a1[s] += wv.x * h4.x + wv.y * h4.y + wv.z * h4.z + wv.w * h4.w;
            }
        }
        #pragma unroll
        for (int s = 0; s < 8; ++s)
            s_fc1[(sh * 8 + s) * 256 + f] = fmaxf(a1[s], 0.0f);
    }
    __syncthreads();

    if (t < NSAMP * 10) {
        const int s = t / 10, a = t % 10;
        float acc2 = fc2_b[a];
        for (int f4 = 0; f4 < 256 / 4; ++f4) {
            const float4 wv = *(const float4*)&fc2_W[a * 256 + f4 * 4];
            const float4 v  = *(const float4*)&s_fc1[s * 256 + f4 * 4];
            acc2 += wv.x * v.x + wv.y * v.y + wv.z * v.z + wv.w * v.w;
        }
        s_logit[s * 10 + a] = acc2;
    }
    __syncthreads();

    if (t < NSAMP) {
        float m = -1e30f;
        #pragma unroll
        for (int a = 0; a < 10; ++a) m = fmaxf(m, s_logit[t * 10 + a]);
        float sum = 0.0f;
        #pragma unroll
        for (int a = 0; a < 10; ++a) sum += __expf(s_logit[t * 10 + a] - m);
        const float lse = m + __logf(sum);
        #pragma unroll
        for (int a = 0; a < 10; ++a)
            out[(s_base + t) * 10 + a] = s_logit[t * 10 + a] - lse;
    }
}

extern "C" void kernel_launch(void* const* d_in, const int* in_sizes, int n_in,
                              void* d_out, int out_size, void* d_ws, size_t ws_size,
                              hipStream_t stream)
{
    (void)d_ws; (void)ws_size; (void)n_in; (void)out_size;

    const float* x   = (const float*)d_in[0];
    const float* Wih = (const float*)d_in[1];
    const float* Whh = (const float*)d_in[2];
    const float* bih = (const float*)d_in[3];
    const float* bhh = (const float*)d_in[4];
    const float* f1w = (const float*)d_in[5];
    const float* f1b = (const float*)d_in[6];
    const float* f2w = (const float*)d_in[7];
    const float* f2b = (const float*)d_in[8];

    const int mb = in_sizes[0] / (NOBJ * DDIM);   // 8192
    dim3 grid(mb / NSAMP), block(BLOCK);
    subset_lstm_bfs_kernel<<<grid, block, 0, stream>>>(
        x, Wih, Whh, bih, bhh, f1w, f1b, f2w, f2b, (float*)d_out);
}